// Round 6
// baseline (542.497 us; speedup 1.0000x reference)
//
#include <hip/hip_runtime.h>
#include <hip/hip_bf16.h>

#define BATCH 32
#define CIN   256
#define COUT  256
#define Hd    56
#define Wd    56
#define HW    (Hd*Wd)

typedef __attribute__((ext_vector_type(8))) short bf16x8;
typedef __attribute__((ext_vector_type(4))) float f32x4;

typedef const __attribute__((address_space(1))) void* gas1_t;
typedef __attribute__((address_space(3))) void* las3_t;

__device__ __forceinline__ unsigned short f2bf_rne(float f) {
    unsigned u = __builtin_bit_cast(unsigned, f);
    u += 0x7fffu + ((u >> 16) & 1u);
    return (unsigned short)(u >> 16);
}

// ---------------------------------------------------------------------------
// Weight prep: Wc[np][kp] center, Wg[np][t][j] off-center, bsum[np].
// permutation: np = (n%4)*64 + n/4 ; kp likewise.
// ---------------------------------------------------------------------------
__global__ void hetconv_prep(const float* __restrict__ W, const float* __restrict__ b,
                             unsigned short* __restrict__ Wc,
                             unsigned short* __restrict__ Wg,
                             float* __restrict__ bsum) {
    const int np = blockIdx.x;
    const int lane = threadIdx.x;
    const int r = np >> 6;
    const int n = ((np & 63) << 2) | r;

    float s = 0.f;
    for (int i = lane; i < CIN; i += 64) s += b[n * CIN + i];
    #pragma unroll
    for (int off = 32; off > 0; off >>= 1) s += __shfl_down(s, off, 64);
    if (lane == 0) bsum[np] = s;

    for (int kp = lane; kp < CIN; kp += 64) {
        int i = ((kp & 63) << 2) | (kp >> 6);
        Wc[np * CIN + kp] = f2bf_rne(W[(n * CIN + i) * 9 + 4]);
    }
    for (int u = lane; u < 8 * 64; u += 64) {
        int t = u >> 6, j = u & 63;
        int tap = t + (t >= 4);
        int i = (j << 2) | r;
        Wg[np * 512 + u] = f2bf_rne(W[(n * CIN + i) * 9 + tap]);
    }
}

// ---------------------------------------------------------------------------
// x convert (R4 layout, correctness-proven): xb[b][pass4][row 58 (0,57 zero)]
// [col 64 (56-63 zero)][64 ch bf16, octet-XOR-swizzled by col&7].
// pass == input residue; octet g holds channels ic = (g*8+e)*4 + pass.
// ---------------------------------------------------------------------------
__global__ __launch_bounds__(512) void hetconv_xconv(const float* __restrict__ x,
                                                     unsigned short* __restrict__ xb) {
    const int bid = blockIdx.x;
    const int b  = bid / 58;
    const int pr = bid % 58;
    const int tid = threadIdx.x;
    const int col = tid & 63;
    const int wid = tid >> 6;
    const int grow = pr - 1;
    const bool ok = (grow >= 0) && (grow < Hd) && (col < Wd);
    const float* xp = x + (size_t)b * CIN * HW + (size_t)grow * Wd + col;

    #pragma unroll
    for (int rd = 0; rd < 4; ++rd) {
        int octG = rd * 8 + wid;          // [0,32)
        int pass = octG >> 3;             // residue
        int g    = octG & 7;
        bf16x8 pk;
        #pragma unroll
        for (int e = 0; e < 8; ++e) {
            int j = g * 8 + e;
            int ic = (j << 2) | pass;
            float f = ok ? xp[(size_t)ic * HW] : 0.f;
            pk[e] = (short)f2bf_rne(f);
        }
        size_t dst = ((size_t)(b * 4 + pass) * 58 + pr) * 4096
                   + col * 64 + ((g ^ (col & 7)) * 8);
        *reinterpret_cast<bf16x8*>(xb + dst) = pk;
    }
}

// ---------------------------------------------------------------------------
// Stage this wave's fixed 4 chunks (1/8) of a 32 KB slab -> LDS.
// Compile-time chunk count so the compiler can emit counted vmcnt waits.
// ---------------------------------------------------------------------------
__device__ __forceinline__ void stage_q(const unsigned short* __restrict__ xb,
                                        unsigned short* lds_dst,
                                        int b, int tr, int p, int wid, int lane) {
    const unsigned short* slab = xb + ((size_t)((b * 4 + p) * 58 + tr)) * 4096;
    #pragma unroll
    for (int i = 0; i < 4; ++i) {
        int vbase = (wid * 4 + i) * 64;           // 16B units, wave-uniform
        __builtin_amdgcn_global_load_lds(
            (gas1_t)(slab + (size_t)(vbase + lane) * 8),
            (las3_t)(lds_dst + vbase * 8), 16, 0, 0);
    }
}

// ---------------------------------------------------------------------------
// Main: 512 blocks = 32 b x 16 rowgroups (12x2 + 4x1 two-row tiles), 64 KB
// LDS dbuf -> 2 blocks/CU.  8 waves = (row h) x (out-residue r).
// Step (tile t, pass p of 64 ch).  Per-wave issue order (vmcnt is per-wave):
//   non-grouped: [8 Wc af loads][4 staging chunks][dense, counted vmcnt]
//   grouped(r==p): [8 af][dense][grouped, in-loop Wg][4 staging chunks]
// End of step: vmcnt(0) + barrier.  Tile end: LDS-staged float4 epilogue.
// ---------------------------------------------------------------------------
__global__ __launch_bounds__(512, 4) void hetconv_main(const unsigned short* __restrict__ xb,
                             const unsigned short* __restrict__ Wc,
                             const unsigned short* __restrict__ Wg,
                             const float* __restrict__ bsum,
                             float* __restrict__ y) {
    __shared__ unsigned short xs[2][16384];   // 2 x 32 KB

    const int bid = blockIdx.x;
    const int b   = bid >> 4;
    const int rg  = bid & 15;
    const int tr0 = (rg < 12) ? rg * 4 : 48 + (rg - 12) * 2;
    const int T   = (rg < 12) ? 2 : 1;
    const int NS  = T * 4;

    const int tid  = threadIdx.x;
    const int lane = tid & 63;
    const int wid  = tid >> 6;
    const int h = wid & 1;
    const int r = wid >> 1;
    const int l15 = lane & 15;
    const int l4  = lane >> 4;

    f32x4 acc[4][4];
    #pragma unroll
    for (int i = 0; i < 4; ++i)
        #pragma unroll
        for (int j = 0; j < 4; ++j) acc[i][j] = f32x4{0.f, 0.f, 0.f, 0.f};

    // prologue: stage (tile0, pass0), drain once
    stage_q(xb, xs[0], b, tr0, 0, wid, lane);
    asm volatile("s_waitcnt vmcnt(0)" ::: "memory");
    __builtin_amdgcn_s_barrier();

    for (int st = 0; st < NS; ++st) {
        const int t  = st >> 2;
        const int p  = st & 3;
        const int tr = tr0 + t * 2;
        const unsigned short* bufC = xs[st & 1];
        unsigned short*       bufN = xs[(st & 1) ^ 1];
        const bool grouped = (r == p);
        const bool havePref = (st + 1 < NS);
        const int trN = tr0 + ((st + 1) >> 2) * 2;
        const int pN  = (st + 1) & 3;

        // ---- dense A-frags for this pass, issued FIRST (before staging) ----
        bf16x8 af[2][4];
        #pragma unroll
        for (int ks = 0; ks < 2; ++ks)
            #pragma unroll
            for (int mf = 0; mf < 4; ++mf) {
                int m = r * 64 + mf * 16 + l15;
                af[ks][mf] = *reinterpret_cast<const bf16x8*>(
                    Wc + (size_t)m * 256 + p * 64 + ks * 32 + l4 * 8);
            }
        __builtin_amdgcn_sched_barrier(0);

        // ---- non-grouped waves: stage now (af already queued ahead) ----
        if (!grouped && havePref)
            stage_q(xb, bufN, b, trN, pN, wid, lane);
        __builtin_amdgcn_sched_barrier(0);

        // ---- dense center-tap GEMM: 2 K-steps of 32 channels ----
        {
            const int srow = (h + 1) * 64;
            #pragma unroll
            for (int ks = 0; ks < 2; ++ks) {
                #pragma unroll
                for (int nf = 0; nf < 4; ++nf) {
                    int s = srow + nf * 16 + l15;
                    int o = ks * 4 + l4;
                    int addr = s * 128 + ((o ^ (s & 7)) << 4);
                    bf16x8 bb = *reinterpret_cast<const bf16x8*>(
                        reinterpret_cast<const char*>(bufC) + addr);
                    #pragma unroll
                    for (int mf = 0; mf < 4; ++mf)
                        acc[mf][nf] = __builtin_amdgcn_mfma_f32_16x16x32_bf16(
                            af[ks][mf], bb, acc[mf][nf], 0, 0, 0);
                }
            }
        }

        // ---- grouped off-center taps (waves r == p; no staging queued) ----
        if (grouped) {
            #pragma unroll
            for (int idx = 0; idx < 16; ++idx) {
                const int t8  = idx >> 1;
                const int ks2 = idx & 1;
                const int tap = t8 + (t8 >= 4);
                const int dy = tap / 3 - 1;
                const int dx = tap % 3 - 1;
                const int srow = (h + 1 + dy) * 64;
                bf16x8 ag[4];
                #pragma unroll
                for (int mf = 0; mf < 4; ++mf) {
                    int m = r * 64 + mf * 16 + l15;
                    ag[mf] = *reinterpret_cast<const bf16x8*>(
                        Wg + ((size_t)m * 8 + t8) * 64 + ks2 * 32 + l4 * 8);
                }
                #pragma unroll
                for (int nf = 0; nf < 4; ++nf) {
                    int c2 = nf * 16 + l15 + dx;
                    c2 = ((unsigned)c2 < 64u) ? c2 : 56;   // col 56 is zero pad
                    int s = srow + c2;
                    int o = ks2 * 4 + l4;
                    int addr = s * 128 + ((o ^ (s & 7)) << 4);
                    bf16x8 bb = *reinterpret_cast<const bf16x8*>(
                        reinterpret_cast<const char*>(bufC) + addr);
                    #pragma unroll
                    for (int mf = 0; mf < 4; ++mf)
                        acc[mf][nf] = __builtin_amdgcn_mfma_f32_16x16x32_bf16(
                            ag[mf], bb, acc[mf][nf], 0, 0, 0);
                }
            }
            // grouped waves stage last (their vmcnt(0) below covers it)
            if (havePref)
                stage_q(xb, bufN, b, trN, pN, wid, lane);
        }

        asm volatile("s_waitcnt vmcnt(0)" ::: "memory");
        __builtin_amdgcn_s_barrier();

        // ---- tile epilogue (after pass 3): staged coalesced stores ----
        if (p == 3) {
            float* lf = reinterpret_cast<float*>(const_cast<unsigned short*>(bufC));
            #pragma unroll
            for (int q = 0; q < 4; ++q) {
                if (r == q) {
                    #pragma unroll
                    for (int mf = 0; mf < 4; ++mf) {
                        #pragma unroll
                        for (int j = 0; j < 4; ++j) {
                            int npl = mf * 16 + l4 * 4 + j;
                            float bias = bsum[q * 64 + npl];
                            #pragma unroll
                            for (int nf = 0; nf < 4; ++nf) {
                                int col = nf * 16 + l15;
                                if (col < Wd)
                                    lf[npl * 116 + h * 56 + col] = acc[mf][nf][j] + bias;
                            }
                            #pragma unroll
                            for (int nf = 0; nf < 4; ++nf) acc[mf][nf][j] = 0.f;
                        }
                    }
                }
                __syncthreads();
                #pragma unroll
                for (int it = 0; it < 4; ++it) {
                    int v = it * 512 + tid;           // 64 npl x 28 float4
                    if (v < 1792) {
                        int npl = v / 28;
                        int f   = v % 28;
                        int row = (f >= 14) ? 1 : 0;
                        int c4  = f - row * 14;
                        int n = (npl << 2) | q;
                        f32x4 val = *reinterpret_cast<const f32x4*>(lf + npl * 116 + f * 4);
                        *reinterpret_cast<f32x4*>(
                            y + (((size_t)b * COUT + n) * Hd + (tr + row)) * Wd + c4 * 4) = val;
                    }
                }
                __syncthreads();
            }
        }
    }
}

extern "C" void kernel_launch(void* const* d_in, const int* in_sizes, int n_in,
                              void* d_out, int out_size, void* d_ws, size_t ws_size,
                              hipStream_t stream) {
    const float* x = (const float*)d_in[0];
    const float* W = (const float*)d_in[1];
    const float* b = (const float*)d_in[2];
    float* y = (float*)d_out;

    unsigned short* Wc   = (unsigned short*)d_ws;                        // 131072 B
    unsigned short* Wg   = (unsigned short*)((char*)d_ws + 131072);      // 262144 B
    float*          bsum = (float*)((char*)d_ws + 393216);               // 1024 B
    unsigned short* xb   = (unsigned short*)((char*)d_ws + 394240);      // 60,817,408 B

    hipLaunchKernelGGL(hetconv_prep,  dim3(256),        dim3(64),  0, stream, W, b, Wc, Wg, bsum);
    hipLaunchKernelGGL(hetconv_xconv, dim3(BATCH * 58), dim3(512), 0, stream, x, xb);
    hipLaunchKernelGGL(hetconv_main,  dim3(512),        dim3(512), 0, stream, xb, Wc, Wg, bsum, y);
}

// Round 7
// 305.074 us; speedup vs baseline: 1.7782x; 1.7782x over previous
//
#include <hip/hip_runtime.h>
#include <hip/hip_bf16.h>

#define BATCH 32
#define CIN   256
#define COUT  256
#define Hd    56
#define Wd    56
#define HW    (Hd*Wd)

typedef __attribute__((ext_vector_type(8))) short bf16x8;
typedef __attribute__((ext_vector_type(4))) float f32x4;

typedef const __attribute__((address_space(1))) void* gas1_t;
typedef __attribute__((address_space(3))) void* las3_t;

__device__ __forceinline__ unsigned short f2bf_rne(float f) {
    unsigned u = __builtin_bit_cast(unsigned, f);
    u += 0x7fffu + ((u >> 16) & 1u);
    return (unsigned short)(u >> 16);
}

// ---------------------------------------------------------------------------
// Weight prep.  np = (n%4)*64 + n/4.
// Wc2[np][p][kq]: center taps in pass-interleaved order:
//   pass p (0..3) holds, for each residue rr, channels j = p*16 + jj;
//   kq = rr*16 + jj  ->  ic = (p*16 + jj)*4 + rr.
// Wg[np][t8][j]: off-center taps, j in [0,64), ic = 4j + r (r = np>>6).
// bsum[np] = sum_i b[n][i].
// ---------------------------------------------------------------------------
__global__ void hetconv_prep(const float* __restrict__ W, const float* __restrict__ b,
                             unsigned short* __restrict__ Wc2,
                             unsigned short* __restrict__ Wg,
                             float* __restrict__ bsum) {
    const int np = blockIdx.x;
    const int lane = threadIdx.x;
    const int r = np >> 6;
    const int n = ((np & 63) << 2) | r;

    float s = 0.f;
    for (int i = lane; i < CIN; i += 64) s += b[n * CIN + i];
    #pragma unroll
    for (int off = 32; off > 0; off >>= 1) s += __shfl_down(s, off, 64);
    if (lane == 0) bsum[np] = s;

    for (int kidx = lane; kidx < CIN; kidx += 64) {
        int p  = kidx >> 6;
        int kq = kidx & 63;
        int rr = kq >> 4, jj = kq & 15;
        int ic = (p * 16 + jj) * 4 + rr;
        Wc2[np * CIN + kidx] = f2bf_rne(W[(n * CIN + ic) * 9 + 4]);
    }
    for (int u = lane; u < 8 * 64; u += 64) {
        int t = u >> 6, j = u & 63;
        int tap = t + (t >= 4);
        int i = (j << 2) | r;
        Wg[np * 512 + u] = f2bf_rne(W[(n * CIN + i) * 9 + tap]);
    }
}

// ---------------------------------------------------------------------------
// x convert: xb[b][p 4][row 58 (0,57 zero)][col 64 (56-63 zero)][64ch bf16,
// octet-XOR-swizzled by col&7].  Pass p, octet 'oct', elem e:
//   kq = oct*8+e; rr = kq>>4; jj = kq&15; ic = (p*16+jj)*4 + rr.
// ---------------------------------------------------------------------------
__global__ __launch_bounds__(512) void hetconv_xconv(const float* __restrict__ x,
                                                     unsigned short* __restrict__ xb) {
    const int bid = blockIdx.x;
    const int b  = bid / 58;
    const int pr = bid % 58;
    const int tid = threadIdx.x;
    const int col = tid & 63;
    const int wid = tid >> 6;
    const int grow = pr - 1;
    const bool ok = (grow >= 0) && (grow < Hd) && (col < Wd);
    const float* xp = x + (size_t)b * CIN * HW + (size_t)grow * Wd + col;

    #pragma unroll
    for (int rd = 0; rd < 4; ++rd) {
        int octG = rd * 8 + wid;          // [0,32)
        int p    = octG >> 3;
        int oct  = octG & 7;
        bf16x8 pk;
        #pragma unroll
        for (int e = 0; e < 8; ++e) {
            int kq = oct * 8 + e;
            int rr = kq >> 4, jj = kq & 15;
            int ic = (p * 16 + jj) * 4 + rr;
            float f = ok ? xp[(size_t)ic * HW] : 0.f;
            pk[e] = (short)f2bf_rne(f);
        }
        size_t dst = ((size_t)(b * 4 + p) * 58 + pr) * 4096
                   + col * 64 + ((oct ^ (col & 7)) * 8);
        *reinterpret_cast<bf16x8*>(xb + dst) = pk;
    }
}

// ---------------------------------------------------------------------------
// Grouped helpers: tap-pair tp covers off-center taps t8 = 2tp, 2tp+1
// (K=32 MFMA: lanes l4<2 -> tap a, l4>=2 -> tap b).
// ---------------------------------------------------------------------------
__device__ __forceinline__ void load_ag(const unsigned short* __restrict__ Wg,
                                        int tp, int p, int r, int l15, int l4,
                                        bf16x8 (&ag)[4]) {
    const int t8 = tp * 2 + (l4 >> 1);
    #pragma unroll
    for (int mf = 0; mf < 4; ++mf) {
        int m = r * 64 + mf * 16 + l15;
        ag[mf] = *reinterpret_cast<const bf16x8*>(
            Wg + ((size_t)m * 8 + t8) * 64 + p * 16 + (l4 & 1) * 8);
    }
}

__device__ __forceinline__ void mfma_pair(const unsigned short* bufC, int tp,
                                          const bf16x8 (&ag)[4], int h, int colb,
                                          int r, int l15, int l4,
                                          f32x4 (&acc)[4][2]) {
    const int hi  = l4 >> 1;
    const int t8  = tp * 2 + hi;
    const int tap = t8 + (t8 >= 4);
    const int dy  = tap / 3 - 1;
    const int dx  = tap % 3 - 1;
    const int lr  = h + 1 + dy;
    const int oct = r * 2 + (l4 & 1);
    #pragma unroll
    for (int nf = 0; nf < 2; ++nf) {
        int col2 = colb + nf * 16 + l15 + dx;
        col2 = ((unsigned)col2 < 64u) ? col2 : 56;      // col 56 is zero pad
        int pix  = lr * 64 + col2;
        int addr = pix * 128 + ((oct ^ (col2 & 7)) << 4);
        bf16x8 bb = *reinterpret_cast<const bf16x8*>(
            reinterpret_cast<const char*>(bufC) + addr);
        #pragma unroll
        for (int mf = 0; mf < 4; ++mf)
            acc[mf][nf] = __builtin_amdgcn_mfma_f32_16x16x32_bf16(
                ag[mf], bb, acc[mf][nf], 0, 0, 0);
    }
}

// ---------------------------------------------------------------------------
// Main: 896 blocks = 32 b x 28 two-row tiles.  1024 threads = 16 waves:
// wave = (h = wid&1, c = (wid>>1)&1, r = wid>>2); per-wave tile 64 out x 32
// cols -> acc[4][2] (32 regs).  4 passes x 64 ch (16 per residue), 32 KB
// slabs double-buffered.  Every wave does dense (16 MFMA) + its residue's
// grouped tap-pairs (32 MFMA) every pass -> balanced barriers.
// ---------------------------------------------------------------------------
__global__ __launch_bounds__(1024) void hetconv_main(const unsigned short* __restrict__ xb,
                             const unsigned short* __restrict__ Wc2,
                             const unsigned short* __restrict__ Wg,
                             const float* __restrict__ bsum,
                             float* __restrict__ y) {
    __shared__ unsigned short xs[2][16384];   // 2 x 32 KB (also epilogue scratch)

    const int bid = blockIdx.x;
    const int b   = bid / 28;
    const int tr  = (bid % 28) * 2;

    const int tid  = threadIdx.x;
    const int lane = tid & 63;
    const int wid  = tid >> 6;
    const int h = wid & 1;
    const int c = (wid >> 1) & 1;
    const int r = wid >> 2;
    const int l15 = lane & 15;
    const int l4  = lane >> 4;
    const int colb = c * 32;

    f32x4 acc[4][2];
    #pragma unroll
    for (int i = 0; i < 4; ++i)
        #pragma unroll
        for (int j = 0; j < 2; ++j) acc[i][j] = f32x4{0.f, 0.f, 0.f, 0.f};

    // ---- stage helper: pass p slab (4 padded rows x 64 col x 64 ch) ----
    auto STAGE = [&](int p, unsigned short* dst) {
        const unsigned short* slab = xb + ((size_t)(b * 4 + p) * 58 + tr) * 4096;
        #pragma unroll
        for (int i = 0; i < 2; ++i) {
            int vbase = (wid * 2 + i) * 64;          // 16B units, wave-uniform
            __builtin_amdgcn_global_load_lds(
                (gas1_t)(slab + (size_t)(vbase + lane) * 8),
                (las3_t)(dst + vbase * 8), 16, 0, 0);
        }
    };

    STAGE(0, xs[0]);
    asm volatile("s_waitcnt vmcnt(0)" ::: "memory");
    __builtin_amdgcn_s_barrier();

    #pragma unroll
    for (int st = 0; st < 4; ++st) {
        const int p = st;
        const unsigned short* bufC = xs[st & 1];
        unsigned short*       bufN = xs[(st & 1) ^ 1];

        // ---- weight issues BEFORE staging (per-wave FIFO: counted waits) ----
        bf16x8 af0[4], af1[4];
        #pragma unroll
        for (int mf = 0; mf < 4; ++mf) {
            int m = r * 64 + mf * 16 + l15;
            af0[mf] = *reinterpret_cast<const bf16x8*>(
                Wc2 + (size_t)m * 256 + p * 64 + l4 * 8);
            af1[mf] = *reinterpret_cast<const bf16x8*>(
                Wc2 + (size_t)m * 256 + p * 64 + 32 + l4 * 8);
        }
        bf16x8 agA[4], agB[4];
        load_ag(Wg, 0, p, r, l15, l4, agA);
        __builtin_amdgcn_sched_barrier(0);

        // ---- stage next slab ----
        if (st < 3) STAGE(st + 1, bufN);
        __builtin_amdgcn_sched_barrier(0);

        // ---- dense: 2 K-steps of 32 ch ----
        {
            const int srow = (h + 1) * 64;
            #pragma unroll
            for (int ks = 0; ks < 2; ++ks) {
                #pragma unroll
                for (int nf = 0; nf < 2; ++nf) {
                    int col = colb + nf * 16 + l15;
                    int pix = srow + col;
                    int addr = pix * 128 + (((ks * 4 + l4) ^ (col & 7)) << 4);
                    bf16x8 bb = *reinterpret_cast<const bf16x8*>(
                        reinterpret_cast<const char*>(bufC) + addr);
                    #pragma unroll
                    for (int mf = 0; mf < 4; ++mf)
                        acc[mf][nf] = __builtin_amdgcn_mfma_f32_16x16x32_bf16(
                            ks ? af1[mf] : af0[mf], bb, acc[mf][nf], 0, 0, 0);
                }
            }
        }

        // ---- grouped: 4 tap-pairs, depth-1 register rotation ----
        load_ag(Wg, 1, p, r, l15, l4, agB);
        mfma_pair(bufC, 0, agA, h, colb, r, l15, l4, acc);
        load_ag(Wg, 2, p, r, l15, l4, agA);
        mfma_pair(bufC, 1, agB, h, colb, r, l15, l4, acc);
        load_ag(Wg, 3, p, r, l15, l4, agB);
        mfma_pair(bufC, 2, agA, h, colb, r, l15, l4, acc);
        mfma_pair(bufC, 3, agB, h, colb, r, l15, l4, acc);

        asm volatile("s_waitcnt vmcnt(0)" ::: "memory");
        __builtin_amdgcn_s_barrier();
    }

    // ---- epilogue: acc -> LDS (128ch x 2rows x 56) -> 448B float4 stores ----
    float* lf = reinterpret_cast<float*>(xs);
    #pragma unroll
    for (int q = 0; q < 2; ++q) {
        if ((r >> 1) == q) {
            #pragma unroll
            for (int mf = 0; mf < 4; ++mf) {
                #pragma unroll
                for (int j = 0; j < 4; ++j) {
                    int npl = mf * 16 + l4 * 4 + j;
                    int chL = (r & 1) * 64 + npl;
                    float bias = bsum[r * 64 + npl];
                    #pragma unroll
                    for (int nf = 0; nf < 2; ++nf) {
                        int col = colb + nf * 16 + l15;
                        if (col < Wd)
                            lf[chL * 112 + h * 56 + col] = acc[mf][nf][j] + bias;
                    }
                }
            }
        }
        __syncthreads();
        #pragma unroll
        for (int it = 0; it < 4; ++it) {
            int v = it * 1024 + tid;          // 128 chL x 28 float4
            if (v < 3584) {
                int chL = v / 28;
                int f   = v % 28;
                int n = ((chL & 63) << 2) | (q * 2 + (chL >> 6));
                f32x4 val = *reinterpret_cast<const f32x4*>(lf + chL * 112 + f * 4);
                *reinterpret_cast<f32x4*>(
                    y + (((size_t)b * COUT + n) * Hd + tr) * Wd + f * 4) = val;
            }
        }
        __syncthreads();
    }
}

extern "C" void kernel_launch(void* const* d_in, const int* in_sizes, int n_in,
                              void* d_out, int out_size, void* d_ws, size_t ws_size,
                              hipStream_t stream) {
    const float* x = (const float*)d_in[0];
    const float* W = (const float*)d_in[1];
    const float* b = (const float*)d_in[2];
    float* y = (float*)d_out;

    unsigned short* Wc2  = (unsigned short*)d_ws;                        // 131072 B
    unsigned short* Wg   = (unsigned short*)((char*)d_ws + 131072);      // 262144 B
    float*          bsum = (float*)((char*)d_ws + 393216);               // 1024 B
    unsigned short* xb   = (unsigned short*)((char*)d_ws + 394240);      // 60,817,408 B

    hipLaunchKernelGGL(hetconv_prep,  dim3(256),        dim3(64),   0, stream, W, b, Wc2, Wg, bsum);
    hipLaunchKernelGGL(hetconv_xconv, dim3(BATCH * 58), dim3(512),  0, stream, x, xb);
    hipLaunchKernelGGL(hetconv_main,  dim3(BATCH * 28), dim3(1024), 0, stream, xb, Wc2, Wg, bsum, y);
}

// Round 8
// 247.478 us; speedup vs baseline: 2.1921x; 1.2327x over previous
//
#include <hip/hip_runtime.h>
#include <hip/hip_bf16.h>

#define BATCH 32
#define CIN   256
#define COUT  256
#define Hd    56
#define Wd    56
#define HW    (Hd*Wd)

typedef __attribute__((ext_vector_type(8))) short bf16x8;
typedef __attribute__((ext_vector_type(4))) float f32x4;

__device__ __forceinline__ unsigned short f2bf_rne(float f) {
    unsigned u = __builtin_bit_cast(unsigned, f);
    u += 0x7fffu + ((u >> 16) & 1u);
    return (unsigned short)(u >> 16);
}

// ---------------------------------------------------------------------------
// Weight prep (R2-proven): Wc[np][kp] center taps, Wg[np][t8][j] off-center,
// bsum[np].  np = (n%4)*64 + n/4 ; kp likewise for inputs.
// ---------------------------------------------------------------------------
__global__ void hetconv_prep(const float* __restrict__ W, const float* __restrict__ b,
                             unsigned short* __restrict__ Wc,
                             unsigned short* __restrict__ Wg,
                             float* __restrict__ bsum) {
    const int np = blockIdx.x;
    const int lane = threadIdx.x;
    const int r = np >> 6;
    const int n = ((np & 63) << 2) | r;

    float s = 0.f;
    for (int i = lane; i < CIN; i += 64) s += b[n * CIN + i];
    #pragma unroll
    for (int off = 32; off > 0; off >>= 1) s += __shfl_down(s, off, 64);
    if (lane == 0) bsum[np] = s;

    for (int kp = lane; kp < CIN; kp += 64) {
        int i = ((kp & 63) << 2) | (kp >> 6);
        Wc[np * CIN + kp] = f2bf_rne(W[(n * CIN + i) * 9 + 4]);
    }
    for (int u = lane; u < 8 * 64; u += 64) {
        int t = u >> 6, j = u & 63;
        int tap = t + (t >= 4);
        int i = (j << 2) | r;
        Wg[np * 512 + u] = f2bf_rne(W[(n * CIN + i) * 9 + tap]);
    }
}

// ---------------------------------------------------------------------------
// x convert: xb[b][row 58 (rows 0,57 zero)][col 64 (56-63 zero)][256 ch bf16,
// permuted kp order, flat/unswizzled].  kp = (c%4)*64 + c/4.
// ---------------------------------------------------------------------------
__global__ __launch_bounds__(512) void hetconv_xconv(const float* __restrict__ x,
                                                     unsigned short* __restrict__ xb) {
    const int bid = blockIdx.x;
    const int b  = bid / 58;
    const int pr = bid % 58;
    const int tid = threadIdx.x;
    const int col = tid & 63;
    const int wid = tid >> 6;
    const int grow = pr - 1;
    const bool ok = (grow >= 0) && (grow < Hd) && (col < Wd);
    const float* xp = x + (size_t)b * CIN * HW + (size_t)grow * Wd + col;
    unsigned short* dstp = xb + ((size_t)(b * 58 + pr) * 64 + col) * 256;

    #pragma unroll
    for (int rd = 0; rd < 4; ++rd) {
        int oct = rd * 8 + wid;           // kp octet [0,32)
        bf16x8 pk;
        #pragma unroll
        for (int e = 0; e < 8; ++e) {
            int kp = oct * 8 + e;
            int ic = ((kp & 63) << 2) | (kp >> 6);
            float f = ok ? xp[(size_t)ic * HW] : 0.f;
            pk[e] = (short)f2bf_rne(f);
        }
        *reinterpret_cast<bf16x8*>(dstp + oct * 8) = pk;
    }
}

// ---------------------------------------------------------------------------
// Main: 896 blocks (XCD-swizzled) = 32 b x 28 two-row tiles.  512 threads =
// 8 waves = (row h) x (out-residue r).  NO LDS staging, NO in-loop barriers:
// B-frags read directly from pixel-major xb via L1/L2 (per-pass footprint
// ~64 KB, cache-fit); A-frags from L2-resident Wc/Wg.  Every wave does 384
// MFMAs total (balanced).  Single barrier pair at the R2-proven epilogue.
// ---------------------------------------------------------------------------
__global__ __launch_bounds__(512, 2) void hetconv_main(const unsigned short* __restrict__ xb,
                             const unsigned short* __restrict__ Wc,
                             const unsigned short* __restrict__ Wg,
                             const float* __restrict__ bsum,
                             float* __restrict__ y) {
    __shared__ float lf[128 * 116];       // 59,392 B epilogue scratch

    const int bid  = blockIdx.x;
    const int work = (bid & 7) * 112 + (bid >> 3);   // XCD-contiguous tiles
    const int b    = work / 28;
    const int tr   = (work % 28) * 2;

    const int tid  = threadIdx.x;
    const int lane = tid & 63;
    const int wid  = tid >> 6;
    const int h = wid & 1;
    const int r = wid >> 1;
    const int l15 = lane & 15;
    const int l4  = lane >> 4;

    f32x4 acc[4][4];
    #pragma unroll
    for (int i = 0; i < 4; ++i)
        #pragma unroll
        for (int j = 0; j < 4; ++j) acc[i][j] = f32x4{0.f, 0.f, 0.f, 0.f};

    // padded rows tr..tr+3 = image rows tr-1..tr+2 (rows 0,57 are zeros)
    const unsigned short* tile = xb + (size_t)(b * 58 + tr) * 64 * 256;
    const unsigned short* drow = tile + (size_t)(h + 1) * 64 * 256;

    #pragma unroll
    for (int p = 0; p < 2; ++p) {
        // ---- dense center taps: 4 K-steps of 32 channels ----
        #pragma unroll
        for (int ks = 0; ks < 4; ++ks) {
            bf16x8 af[4];
            #pragma unroll
            for (int mf = 0; mf < 4; ++mf) {
                int m = r * 64 + mf * 16 + l15;
                af[mf] = *reinterpret_cast<const bf16x8*>(
                    Wc + (size_t)m * 256 + p * 128 + ks * 32 + l4 * 8);
            }
            #pragma unroll
            for (int nf = 0; nf < 4; ++nf) {
                int col = nf * 16 + l15;
                bf16x8 bb = *reinterpret_cast<const bf16x8*>(
                    drow + col * 256 + p * 128 + ks * 32 + l4 * 8);
                #pragma unroll
                for (int mf = 0; mf < 4; ++mf)
                    acc[mf][nf] = __builtin_amdgcn_mfma_f32_16x16x32_bf16(
                        af[mf], bb, acc[mf][nf], 0, 0, 0);
            }
        }

        // ---- grouped off-center taps (this wave's residue lives in pass p) ----
        if ((r >> 1) == p) {
            #pragma unroll
            for (int t8 = 0; t8 < 8; ++t8) {
                const int tap = t8 + (t8 >= 4);
                const int dy = tap / 3 - 1;
                const int dx = tap % 3 - 1;
                const unsigned short* grow_ = tile + (size_t)(h + 1 + dy) * 64 * 256;
                #pragma unroll
                for (int ks2 = 0; ks2 < 2; ++ks2) {
                    bf16x8 ag[4];
                    #pragma unroll
                    for (int mf = 0; mf < 4; ++mf) {
                        int m = r * 64 + mf * 16 + l15;
                        ag[mf] = *reinterpret_cast<const bf16x8*>(
                            Wg + ((size_t)m * 8 + t8) * 64 + ks2 * 32 + l4 * 8);
                    }
                    #pragma unroll
                    for (int nf = 0; nf < 4; ++nf) {
                        int c2 = nf * 16 + l15 + dx;
                        c2 = ((unsigned)c2 < 64u) ? c2 : 56;   // col 56 is zero pad
                        bf16x8 bb = *reinterpret_cast<const bf16x8*>(
                            grow_ + c2 * 256 + r * 64 + ks2 * 32 + l4 * 8);
                        #pragma unroll
                        for (int mf = 0; mf < 4; ++mf)
                            acc[mf][nf] = __builtin_amdgcn_mfma_f32_16x16x32_bf16(
                                ag[mf], bb, acc[mf][nf], 0, 0, 0);
                    }
                }
            }
        }
    }

    // ---- epilogue (R2-proven): acc -> LDS -> coalesced float4 stores ----
    #pragma unroll
    for (int q = 0; q < 2; ++q) {
        if ((r >> 1) == q) {
            #pragma unroll
            for (int mf = 0; mf < 4; ++mf) {
                #pragma unroll
                for (int j = 0; j < 4; ++j) {
                    int chL = (r & 1) * 64 + mf * 16 + l4 * 4 + j;
                    float bias = bsum[q * 128 + chL];
                    #pragma unroll
                    for (int nf = 0; nf < 4; ++nf) {
                        int col = nf * 16 + l15;
                        if (col < Wd)
                            lf[chL * 116 + h * 56 + col] = acc[mf][nf][j] + bias;
                    }
                }
            }
        }
        __syncthreads();
        #pragma unroll
        for (int it = 0; it < 7; ++it) {
            int v = it * 512 + tid;            // 128 chL x 28 float4
            int chL = v / 28;
            int f   = v % 28;
            int h2  = (f >= 14) ? 1 : 0;
            int colS = (f - h2 * 14) * 4;
            int n = ((chL & 63) << 2) | (q * 2 + (chL >> 6));
            f32x4 val = *reinterpret_cast<const f32x4*>(lf + chL * 116 + f * 4);
            *reinterpret_cast<f32x4*>(
                y + (((size_t)b * COUT + n) * Hd + (tr + h2)) * Wd + colS) = val;
        }
        __syncthreads();
    }
}

extern "C" void kernel_launch(void* const* d_in, const int* in_sizes, int n_in,
                              void* d_out, int out_size, void* d_ws, size_t ws_size,
                              hipStream_t stream) {
    const float* x = (const float*)d_in[0];
    const float* W = (const float*)d_in[1];
    const float* b = (const float*)d_in[2];
    float* y = (float*)d_out;

    unsigned short* Wc   = (unsigned short*)d_ws;                        // 131072 B
    unsigned short* Wg   = (unsigned short*)((char*)d_ws + 131072);      // 262144 B
    float*          bsum = (float*)((char*)d_ws + 393216);               // 1024 B
    unsigned short* xb   = (unsigned short*)((char*)d_ws + 394240);      // 60,817,408 B

    hipLaunchKernelGGL(hetconv_prep,  dim3(256),        dim3(64),  0, stream, W, b, Wc, Wg, bsum);
    hipLaunchKernelGGL(hetconv_xconv, dim3(BATCH * 58), dim3(512), 0, stream, x, xb);
    hipLaunchKernelGGL(hetconv_main,  dim3(BATCH * 28), dim3(512), 0, stream, xb, Wc, Wg, bsum, y);
}

// Round 9
// 177.144 us; speedup vs baseline: 3.0625x; 1.3970x over previous
//
#include <hip/hip_runtime.h>
#include <hip/hip_bf16.h>

#define BATCH 32
#define CIN   256
#define COUT  256
#define Hd    56
#define Wd    56
#define HW    (Hd*Wd)

typedef __attribute__((ext_vector_type(8))) short bf16x8;
typedef __attribute__((ext_vector_type(4))) float f32x4;

typedef const __attribute__((address_space(1))) void* gas1_t;
typedef __attribute__((address_space(3))) void* las3_t;

__device__ __forceinline__ unsigned short f2bf_rne(float f) {
    unsigned u = __builtin_bit_cast(unsigned, f);
    u += 0x7fffu + ((u >> 16) & 1u);
    return (unsigned short)(u >> 16);
}

// ---------------------------------------------------------------------------
// bsum[np] = sum_i b[n][i],  np = (n%4)*64 + n/4.
// ---------------------------------------------------------------------------
__global__ void hetconv_bsum(const float* __restrict__ b, float* __restrict__ bsum) {
    const int np = blockIdx.x;
    const int lane = threadIdx.x;
    const int n = ((np & 63) << 2) | (np >> 6);
    float s = 0.f;
    for (int i = lane; i < CIN; i += 64) s += b[n * CIN + i];
    #pragma unroll
    for (int off = 32; off > 0; off >>= 1) s += __shfl_down(s, off, 64);
    if (lane == 0) bsum[np] = s;
}

// ---------------------------------------------------------------------------
// Weight prep, fragment-ordered lane-linear layout (contiguous 1 KB per
// A-frag wave-load):
//  Wc3 chunk u = ((r*2+p)*4+ks)*4+mf  (128 chunks x 1 KB):
//    lane (l15,l4), e: np=r*64+mf*16+l15; kp=p*128+ks*32+l4*8+e;
//    dst short = u*512 + lane*8 + e   (lane = l4*16+l15)
//  Wg3 chunk u2 = ((r*8+t8)*2+ks2)*4+mf (256 chunks x 1 KB):
//    np=r*64+mf*16+l15; j=ks2*32+l4*8+e; ic=4j+r; tap=t8+(t8>=4)
// ---------------------------------------------------------------------------
__global__ void hetconv_wprep(const float* __restrict__ W,
                              unsigned short* __restrict__ Wc3,
                              unsigned short* __restrict__ Wg3) {
    const int bid = blockIdx.x;
    const int lane = threadIdx.x;
    const int l15 = lane & 15;
    const int l4  = lane >> 4;

    if (bid < 128) {                     // Wc3
        const int mf = bid & 3;
        const int ks = (bid >> 2) & 3;
        const int p  = (bid >> 4) & 1;
        const int r  = bid >> 5;
        const int np = r * 64 + mf * 16 + l15;
        const int n  = ((np & 63) << 2) | r;
        #pragma unroll
        for (int e = 0; e < 8; ++e) {
            int kp = p * 128 + ks * 32 + l4 * 8 + e;
            int ic = ((kp & 63) << 2) | (kp >> 6);
            Wc3[bid * 512 + lane * 8 + e] = f2bf_rne(W[(n * CIN + ic) * 9 + 4]);
        }
    } else {                             // Wg3
        const int u2 = bid - 128;
        const int mf  = u2 & 3;
        const int ks2 = (u2 >> 2) & 1;
        const int t8  = (u2 >> 3) & 7;
        const int r   = u2 >> 6;
        const int np = r * 64 + mf * 16 + l15;
        const int n  = ((np & 63) << 2) | r;
        const int tap = t8 + (t8 >= 4);
        #pragma unroll
        for (int e = 0; e < 8; ++e) {
            int j  = ks2 * 32 + l4 * 8 + e;
            int ic = (j << 2) | r;
            Wg3[u2 * 512 + lane * 8 + e] = f2bf_rne(W[(n * CIN + ic) * 9 + tap]);
        }
    }
}

// ---------------------------------------------------------------------------
// x convert (R2 layout, proven): xb[b][pass2][row 58 (rows 0,57 zero)]
// [col 64 (56-63 zero)][128 ch bf16, octet-XOR-swizzled by col&7].
// ---------------------------------------------------------------------------
__global__ __launch_bounds__(512) void hetconv_xconv(const float* __restrict__ x,
                                                     unsigned short* __restrict__ xb) {
    const int bid = blockIdx.x;
    const int b  = bid / 58;
    const int pr = bid % 58;
    const int tid = threadIdx.x;
    const int col = tid & 63;
    const int wid = tid >> 6;
    const int grow = pr - 1;
    const bool ok = (grow >= 0) && (grow < Hd) && (col < Wd);
    const float* xp = x + (size_t)b * CIN * HW + (size_t)grow * Wd + col;

    #pragma unroll
    for (int rd = 0; rd < 4; ++rd) {
        int octG = rd * 8 + wid;
        int pass = octG >> 4;
        int g    = octG & 15;
        bf16x8 pk;
        #pragma unroll
        for (int e = 0; e < 8; ++e) {
            int kp = pass * 128 + g * 8 + e;
            int ic = ((kp & 63) << 2) | (kp >> 6);
            float f = ok ? xp[(size_t)ic * HW] : 0.f;
            pk[e] = (short)f2bf_rne(f);
        }
        size_t dst = ((size_t)(b * 2 + pass) * 58 + pr) * 8192
                   + col * 128 + ((g ^ (col & 7)) * 8);
        *reinterpret_cast<bf16x8*>(xb + dst) = pk;
    }
}

// ---------------------------------------------------------------------------
// Main (R2 skeleton, verbatim except A-frag loads now contiguous lane-linear):
// block = (batch, 2-row tile); 8 waves = (row h) x (residue r); two 128-ch
// passes staged in 64 KB LDS via global_load_lds.
// ---------------------------------------------------------------------------
__global__ __launch_bounds__(512) void hetconv_main(const unsigned short* __restrict__ xb,
                             const unsigned short* __restrict__ Wc3,
                             const unsigned short* __restrict__ Wg3,
                             const float* __restrict__ bsum,
                             float* __restrict__ y) {
    __shared__ unsigned short xs[4 * 64 * 128];   // 64 KB

    const int bid = blockIdx.x;
    const int b   = bid / 28;
    const int R0  = (bid % 28) * 2;
    const int tid = threadIdx.x;
    const int lane = tid & 63;
    const int wid  = tid >> 6;
    const int h = wid & 1;
    const int r = wid >> 1;
    const int l15 = lane & 15;
    const int l4  = lane >> 4;

    f32x4 acc[4][4];
    #pragma unroll
    for (int i = 0; i < 4; ++i)
        #pragma unroll
        for (int j = 0; j < 4; ++j) acc[i][j] = f32x4{0.f, 0.f, 0.f, 0.f};

    for (int pass = 0; pass < 2; ++pass) {
        // ---- stage: 64 KB contiguous slab -> LDS, 8 x 16B per thread ----
        const unsigned short* slab = xb + ((size_t)(b * 2 + pass) * 58 + R0) * 8192;
        #pragma unroll
        for (int rd = 0; rd < 8; ++rd) {
            int vbase = rd * 512 + wid * 64;      // 16B-unit index, wave-uniform
            __builtin_amdgcn_global_load_lds(
                (gas1_t)(slab + (size_t)(vbase + lane) * 8),
                (las3_t)(xs + vbase * 8), 16, 0, 0);
        }
        __syncthreads();

        // ---- dense center-tap GEMM: 4 K-steps of 32 channels ----
        {
            const int srow = (h + 1) * 64;
            #pragma unroll
            for (int ks = 0; ks < 4; ++ks) {
                bf16x8 a[4];
                #pragma unroll
                for (int mf = 0; mf < 4; ++mf) {
                    int chunk = ((r * 2 + pass) * 4 + ks) * 4 + mf;
                    a[mf] = *reinterpret_cast<const bf16x8*>(
                        Wc3 + ((size_t)chunk << 9) + lane * 8);
                }
                #pragma unroll
                for (int nf = 0; nf < 4; ++nf) {
                    int s = srow + nf * 16 + l15;
                    int o = ks * 4 + l4;
                    int addr = s * 256 + ((o ^ (s & 7)) << 4);
                    bf16x8 bb = *reinterpret_cast<const bf16x8*>(
                        reinterpret_cast<const char*>(xs) + addr);
                    #pragma unroll
                    for (int mf = 0; mf < 4; ++mf)
                        acc[mf][nf] = __builtin_amdgcn_mfma_f32_16x16x32_bf16(
                            a[mf], bb, acc[mf][nf], 0, 0, 0);
                }
            }
        }

        // ---- grouped off-center taps (this wave's residue channels) ----
        if ((r >> 1) == pass) {
            const int cbase = (r & 1) * 64;
            #pragma unroll
            for (int t8 = 0; t8 < 8; ++t8) {
                const int tap = t8 + (t8 >= 4);
                const int dy = tap / 3 - 1;
                const int dx = tap % 3 - 1;
                const int srow = (h + 1 + dy) * 64;
                #pragma unroll
                for (int ks2 = 0; ks2 < 2; ++ks2) {
                    bf16x8 a[4];
                    #pragma unroll
                    for (int mf = 0; mf < 4; ++mf) {
                        int chunk = ((r * 8 + t8) * 2 + ks2) * 4 + mf;
                        a[mf] = *reinterpret_cast<const bf16x8*>(
                            Wg3 + ((size_t)chunk << 9) + lane * 8);
                    }
                    #pragma unroll
                    for (int nf = 0; nf < 4; ++nf) {
                        int c2 = nf * 16 + l15 + dx;
                        c2 = ((unsigned)c2 < 64u) ? c2 : 56;   // col 56 is zero pad
                        int s = srow + c2;
                        int o = ((cbase + ks2 * 32) >> 3) + l4;
                        int addr = s * 256 + ((o ^ (s & 7)) << 4);
                        bf16x8 bb = *reinterpret_cast<const bf16x8*>(
                            reinterpret_cast<const char*>(xs) + addr);
                        #pragma unroll
                        for (int mf = 0; mf < 4; ++mf)
                            acc[mf][nf] = __builtin_amdgcn_mfma_f32_16x16x32_bf16(
                                a[mf], bb, acc[mf][nf], 0, 0, 0);
                    }
                }
            }
        }
        __syncthreads();
    }

    // ---- epilogue (R2-proven): acc -> LDS -> coalesced float4 stores ----
    float* lf = reinterpret_cast<float*>(xs);
    #pragma unroll
    for (int q = 0; q < 2; ++q) {
        if ((r >> 1) == q) {
            #pragma unroll
            for (int mf = 0; mf < 4; ++mf) {
                #pragma unroll
                for (int j = 0; j < 4; ++j) {
                    int chL = (r & 1) * 64 + mf * 16 + l4 * 4 + j;
                    float bias = bsum[q * 128 + chL];
                    #pragma unroll
                    for (int nf = 0; nf < 4; ++nf) {
                        int col = nf * 16 + l15;
                        if (col < Wd)
                            lf[chL * 116 + h * 56 + col] = acc[mf][nf][j] + bias;
                    }
                }
            }
        }
        __syncthreads();
        #pragma unroll
        for (int it = 0; it < 7; ++it) {
            int v = it * 512 + tid;            // 128 chL x 28 float4
            int chL = v / 28;
            int f   = v % 28;
            int h2  = (f >= 14) ? 1 : 0;
            int colS = (f - h2 * 14) * 4;
            int n = ((chL & 63) << 2) | (q * 2 + (chL >> 6));
            f32x4 val = *reinterpret_cast<const f32x4*>(lf + chL * 116 + f * 4);
            *reinterpret_cast<f32x4*>(
                y + (((size_t)b * COUT + n) * Hd + (R0 + h2)) * Wd + colS) = val;
        }
        __syncthreads();
    }
}

extern "C" void kernel_launch(void* const* d_in, const int* in_sizes, int n_in,
                              void* d_out, int out_size, void* d_ws, size_t ws_size,
                              hipStream_t stream) {
    const float* x = (const float*)d_in[0];
    const float* W = (const float*)d_in[1];
    const float* b = (const float*)d_in[2];
    float* y = (float*)d_out;

    unsigned short* Wc3  = (unsigned short*)d_ws;                        // 131072 B
    unsigned short* Wg3  = (unsigned short*)((char*)d_ws + 131072);      // 262144 B
    float*          bsum = (float*)((char*)d_ws + 393216);               // 1024 B
    unsigned short* xb   = (unsigned short*)((char*)d_ws + 394240);      // 60,817,408 B

    hipLaunchKernelGGL(hetconv_bsum,  dim3(256),        dim3(64),  0, stream, b, bsum);
    hipLaunchKernelGGL(hetconv_wprep, dim3(384),        dim3(64),  0, stream, W, Wc3, Wg3);
    hipLaunchKernelGGL(hetconv_xconv, dim3(BATCH * 58), dim3(512), 0, stream, x, xb);
    hipLaunchKernelGGL(hetconv_main,  dim3(BATCH * 28), dim3(512), 0, stream, xb, Wc3, Wg3, bsum, y);
}

// Round 10
// 137.223 us; speedup vs baseline: 3.9534x; 1.2909x over previous
//
#include <hip/hip_runtime.h>
#include <hip/hip_bf16.h>

#define BATCH 32
#define CIN   256
#define COUT  256
#define Hd    56
#define Wd    56
#define HW    (Hd*Wd)

typedef __attribute__((ext_vector_type(8))) short bf16x8;
typedef __attribute__((ext_vector_type(4))) float f32x4;

typedef const __attribute__((address_space(1))) void* gas1_t;
typedef __attribute__((address_space(3))) void* las3_t;

__device__ __forceinline__ unsigned short f2bf_rne(float f) {
    unsigned u = __builtin_bit_cast(unsigned, f);
    u += 0x7fffu + ((u >> 16) & 1u);
    return (unsigned short)(u >> 16);
}

// ---------------------------------------------------------------------------
// bsum[np] = sum_i b[n][i],  np = (n%4)*64 + n/4.
// ---------------------------------------------------------------------------
__global__ void hetconv_bsum(const float* __restrict__ b, float* __restrict__ bsum) {
    const int np = blockIdx.x;
    const int lane = threadIdx.x;
    const int n = ((np & 63) << 2) | (np >> 6);
    float s = 0.f;
    for (int i = lane; i < CIN; i += 64) s += b[n * CIN + i];
    #pragma unroll
    for (int off = 32; off > 0; off >>= 1) s += __shfl_down(s, off, 64);
    if (lane == 0) bsum[np] = s;
}

// ---------------------------------------------------------------------------
// Weight prep (R9-proven): fragment-ordered lane-linear chunks of 1 KB.
// ---------------------------------------------------------------------------
__global__ void hetconv_wprep(const float* __restrict__ W,
                              unsigned short* __restrict__ Wc3,
                              unsigned short* __restrict__ Wg3) {
    const int bid = blockIdx.x;
    const int lane = threadIdx.x;
    const int l15 = lane & 15;
    const int l4  = lane >> 4;

    if (bid < 128) {                     // Wc3: chunk = ((r*2+p)*4+ks)*4+mf
        const int mf = bid & 3;
        const int ks = (bid >> 2) & 3;
        const int p  = (bid >> 4) & 1;
        const int r  = bid >> 5;
        const int np = r * 64 + mf * 16 + l15;
        const int n  = ((np & 63) << 2) | r;
        #pragma unroll
        for (int e = 0; e < 8; ++e) {
            int kp = p * 128 + ks * 32 + l4 * 8 + e;
            int ic = ((kp & 63) << 2) | (kp >> 6);
            Wc3[bid * 512 + lane * 8 + e] = f2bf_rne(W[(n * CIN + ic) * 9 + 4]);
        }
    } else {                             // Wg3: chunk = ((r*8+t8)*2+ks2)*4+mf
        const int u2 = bid - 128;
        const int mf  = u2 & 3;
        const int ks2 = (u2 >> 2) & 1;
        const int t8  = (u2 >> 3) & 7;
        const int r   = u2 >> 6;
        const int np = r * 64 + mf * 16 + l15;
        const int n  = ((np & 63) << 2) | r;
        const int tap = t8 + (t8 >= 4);
        #pragma unroll
        for (int e = 0; e < 8; ++e) {
            int j  = ks2 * 32 + l4 * 8 + e;
            int ic = (j << 2) | r;
            Wg3[u2 * 512 + lane * 8 + e] = f2bf_rne(W[(n * CIN + ic) * 9 + tap]);
        }
    }
}

// ---------------------------------------------------------------------------
// x convert (vectorized): same xb layout as R9 --
// xb[b][pass2][row 58 (rows 0,57 zero)][col 64 (56-63 zero)][128 ch bf16,
// octet-XOR-swizzled by col&7].  Thread = (octG, col-quad): 8 float4 loads
// (224B lane-contiguous per channel), in-register transpose, 4 x 16B stores.
// ---------------------------------------------------------------------------
__global__ __launch_bounds__(512) void hetconv_xconv(const float* __restrict__ x,
                                                     unsigned short* __restrict__ xb) {
    const int bid = blockIdx.x;
    const int b  = bid / 58;
    const int pr = bid % 58;
    const int tid = threadIdx.x;
    const int grow = pr - 1;
    const bool ok = (grow >= 0) && (grow < Hd);

    if (tid < 448) {
        const int octG = tid / 14;        // [0,32)
        const int q    = tid % 14;        // col quad [0,14)
        const int pass = octG >> 4;
        const int g    = octG & 15;
        const size_t base = ((size_t)(b * 2 + pass) * 58 + pr) * 8192;

        f32x4 v[8];
        #pragma unroll
        for (int e = 0; e < 8; ++e) {
            int kp = octG * 8 + e;
            int ic = ((kp & 63) << 2) | (kp >> 6);
            v[e] = ok ? *reinterpret_cast<const f32x4*>(
                            x + (size_t)b * CIN * HW + (size_t)ic * HW + grow * Wd + q * 4)
                      : f32x4{0.f, 0.f, 0.f, 0.f};
        }
        #pragma unroll
        for (int i = 0; i < 4; ++i) {
            int col = q * 4 + i;
            bf16x8 pk;
            #pragma unroll
            for (int e = 0; e < 8; ++e) pk[e] = (short)f2bf_rne(v[e][i]);
            *reinterpret_cast<bf16x8*>(xb + base + col * 128 + ((g ^ (col & 7)) * 8)) = pk;
        }
    } else {
        const int u = tid - 448;          // zero the pad cols 56..63
        const int octG = u >> 1;
        const int colh = u & 1;
        const int pass = octG >> 4;
        const int g    = octG & 15;
        const size_t base = ((size_t)(b * 2 + pass) * 58 + pr) * 8192;
        #pragma unroll
        for (int i = 0; i < 4; ++i) {
            int col = 56 + colh * 4 + i;
            bf16x8 z = {0,0,0,0,0,0,0,0};
            *reinterpret_cast<bf16x8*>(xb + base + col * 128 + ((g ^ (col & 7)) * 8)) = z;
        }
    }
}

// ---------------------------------------------------------------------------
// Main: R9 skeleton with single-drain schedule.  Stage BOTH 64 KB pass-slabs
// into 128 KB LDS up front, ONE vmcnt(0)+barrier, then both passes' dense +
// grouped MFMA run as one unbroken stream (weights-only vmem queue ->
// compiler counted waits / pipelining).  Barrier only before the epilogue.
// ---------------------------------------------------------------------------
__global__ __launch_bounds__(512) void hetconv_main(const unsigned short* __restrict__ xb,
                             const unsigned short* __restrict__ Wc3,
                             const unsigned short* __restrict__ Wg3,
                             const float* __restrict__ bsum,
                             float* __restrict__ y) {
    __shared__ unsigned short xs[2][32768];   // 2 x 64 KB (epilogue reuses xs[0])

    const int bid = blockIdx.x;
    const int b   = bid / 28;
    const int R0  = (bid % 28) * 2;
    const int tid = threadIdx.x;
    const int lane = tid & 63;
    const int wid  = tid >> 6;
    const int h = wid & 1;
    const int r = wid >> 1;
    const int l15 = lane & 15;
    const int l4  = lane >> 4;

    f32x4 acc[4][4];
    #pragma unroll
    for (int i = 0; i < 4; ++i)
        #pragma unroll
        for (int j = 0; j < 4; ++j) acc[i][j] = f32x4{0.f, 0.f, 0.f, 0.f};

    // ---- stage both passes, single drain ----
    #pragma unroll
    for (int pass = 0; pass < 2; ++pass) {
        const unsigned short* slab = xb + ((size_t)(b * 2 + pass) * 58 + R0) * 8192;
        #pragma unroll
        for (int rd = 0; rd < 8; ++rd) {
            int vbase = rd * 512 + wid * 64;      // 16B-unit index, wave-uniform
            __builtin_amdgcn_global_load_lds(
                (gas1_t)(slab + (size_t)(vbase + lane) * 8),
                (las3_t)(xs[pass] + vbase * 8), 16, 0, 0);
        }
    }
    asm volatile("s_waitcnt vmcnt(0)" ::: "memory");
    __builtin_amdgcn_s_barrier();

    // ---- both passes, no intervening barrier ----
    #pragma unroll
    for (int pass = 0; pass < 2; ++pass) {
        const unsigned short* xsb = xs[pass];

        // dense center-tap GEMM: 4 K-steps of 32 channels
        {
            const int srow = (h + 1) * 64;
            #pragma unroll
            for (int ks = 0; ks < 4; ++ks) {
                bf16x8 a[4];
                #pragma unroll
                for (int mf = 0; mf < 4; ++mf) {
                    int chunk = ((r * 2 + pass) * 4 + ks) * 4 + mf;
                    a[mf] = *reinterpret_cast<const bf16x8*>(
                        Wc3 + ((size_t)chunk << 9) + lane * 8);
                }
                #pragma unroll
                for (int nf = 0; nf < 4; ++nf) {
                    int s = srow + nf * 16 + l15;
                    int o = ks * 4 + l4;
                    int addr = s * 256 + ((o ^ (s & 7)) << 4);
                    bf16x8 bb = *reinterpret_cast<const bf16x8*>(
                        reinterpret_cast<const char*>(xsb) + addr);
                    #pragma unroll
                    for (int mf = 0; mf < 4; ++mf)
                        acc[mf][nf] = __builtin_amdgcn_mfma_f32_16x16x32_bf16(
                            a[mf], bb, acc[mf][nf], 0, 0, 0);
                }
            }
        }

        // grouped off-center taps (this wave's residue channels)
        if ((r >> 1) == pass) {
            const int cbase = (r & 1) * 64;
            #pragma unroll
            for (int t8 = 0; t8 < 8; ++t8) {
                const int tap = t8 + (t8 >= 4);
                const int dy = tap / 3 - 1;
                const int dx = tap % 3 - 1;
                const int srow = (h + 1 + dy) * 64;
                #pragma unroll
                for (int ks2 = 0; ks2 < 2; ++ks2) {
                    bf16x8 a[4];
                    #pragma unroll
                    for (int mf = 0; mf < 4; ++mf) {
                        int chunk = ((r * 8 + t8) * 2 + ks2) * 4 + mf;
                        a[mf] = *reinterpret_cast<const bf16x8*>(
                            Wg3 + ((size_t)chunk << 9) + lane * 8);
                    }
                    #pragma unroll
                    for (int nf = 0; nf < 4; ++nf) {
                        int c2 = nf * 16 + l15 + dx;
                        c2 = ((unsigned)c2 < 64u) ? c2 : 56;   // col 56 is zero pad
                        int s = srow + c2;
                        int o = ((cbase + ks2 * 32) >> 3) + l4;
                        int addr = s * 256 + ((o ^ (s & 7)) << 4);
                        bf16x8 bb = *reinterpret_cast<const bf16x8*>(
                            reinterpret_cast<const char*>(xsb) + addr);
                        #pragma unroll
                        for (int mf = 0; mf < 4; ++mf)
                            acc[mf][nf] = __builtin_amdgcn_mfma_f32_16x16x32_bf16(
                                a[mf], bb, acc[mf][nf], 0, 0, 0);
                    }
                }
            }
        }
    }
    __syncthreads();

    // ---- epilogue (R2/R9-proven): acc -> LDS -> coalesced float4 stores ----
    float* lf = reinterpret_cast<float*>(xs[0]);
    #pragma unroll
    for (int q = 0; q < 2; ++q) {
        if ((r >> 1) == q) {
            #pragma unroll
            for (int mf = 0; mf < 4; ++mf) {
                #pragma unroll
                for (int j = 0; j < 4; ++j) {
                    int chL = (r & 1) * 64 + mf * 16 + l4 * 4 + j;
                    float bias = bsum[q * 128 + chL];
                    #pragma unroll
                    for (int nf = 0; nf < 4; ++nf) {
                        int col = nf * 16 + l15;
                        if (col < Wd)
                            lf[chL * 116 + h * 56 + col] = acc[mf][nf][j] + bias;
                    }
                }
            }
        }
        __syncthreads();
        #pragma unroll
        for (int it = 0; it < 7; ++it) {
            int v = it * 512 + tid;            // 128 chL x 28 float4
            int chL = v / 28;
            int f   = v % 28;
            int h2  = (f >= 14) ? 1 : 0;
            int colS = (f - h2 * 14) * 4;
            int n = ((chL & 63) << 2) | (q * 2 + (chL >> 6));
            f32x4 val = *reinterpret_cast<const f32x4*>(lf + chL * 116 + f * 4);
            *reinterpret_cast<f32x4*>(
                y + (((size_t)b * COUT + n) * Hd + (R0 + h2)) * Wd + colS) = val;
        }
        __syncthreads();
    }
}

extern "C" void kernel_launch(void* const* d_in, const int* in_sizes, int n_in,
                              void* d_out, int out_size, void* d_ws, size_t ws_size,
                              hipStream_t stream) {
    const float* x = (const float*)d_in[0];
    const float* W = (const float*)d_in[1];
    const float* b = (const float*)d_in[2];
    float* y = (float*)d_out;

    unsigned short* Wc3  = (unsigned short*)d_ws;                        // 131072 B
    unsigned short* Wg3  = (unsigned short*)((char*)d_ws + 131072);      // 262144 B
    float*          bsum = (float*)((char*)d_ws + 393216);               // 1024 B
    unsigned short* xb   = (unsigned short*)((char*)d_ws + 394240);      // 60,817,408 B

    hipLaunchKernelGGL(hetconv_bsum,  dim3(256),        dim3(64),  0, stream, b, bsum);
    hipLaunchKernelGGL(hetconv_wprep, dim3(384),        dim3(64),  0, stream, W, Wc3, Wg3);
    hipLaunchKernelGGL(hetconv_xconv, dim3(BATCH * 58), dim3(512), 0, stream, x, xb);
    hipLaunchKernelGGL(hetconv_main,  dim3(BATCH * 28), dim3(512), 0, stream, xb, Wc3, Wg3, bsum, y);
}